// Round 7
// baseline (415.512 us; speedup 1.0000x reference)
//
#include <hip/hip_runtime.h>
#include <hip/hip_bf16.h>

#define D_DIM 768
#define B_DIM 8192
#define NTILE 64      // 8192/128 row tiles
#define NPAIR 2080    // NTILE*(NTILE+1)/2 symmetric tile pairs
#define BM 128
#define BN 128
#define BK 64
#define SLOTS 512     // per-row global survivor slots
#define S_GATE 640.0f // fixed s-space gate: ~6 sigma above max row 6th-NN s;
                      // exactness is NOT distribution-dependent (cnt<6 -> fallback)

typedef __attribute__((ext_vector_type(8))) short short8;
typedef __attribute__((ext_vector_type(4))) float f32x4;
typedef __attribute__((ext_vector_type(4))) unsigned short ushort4v;

// ws layout (bytes)
#define WS_XB   0                            // bf16[8192*768] = 12,582,912
#define WS_SQ   12582912                     // float[8192]
#define WS_CNT  12615680                     // uint[8192]
#define WS_CAND 12648448                     // float[8192*512] = 16,777,216
#define WS_ACC  29425664                     // float acc + int completion counter

__device__ __forceinline__ void gl_lds16(const void* g, void* lds) {
  __builtin_amdgcn_global_load_lds(
      (const __attribute__((address_space(1))) unsigned int*)g,
      (__attribute__((address_space(3))) unsigned int*)lds, 16, 0, 0);
}

__device__ __forceinline__ float bf2f(unsigned short u) {
  unsigned int x = ((unsigned int)u) << 16;
  float f;
  __builtin_memcpy(&f, &x, 4);
  return f;
}

// maintain v[0..5] = six smallest seen, sorted ascending (v[5] = max)
__device__ __forceinline__ void ins6(float c, float* v) {
  if (c < v[5]) {
    v[5] = c;
#pragma unroll
    for (int s = 5; s > 0; --s) {
      float lo = fminf(v[s - 1], v[s]);
      float hi = fmaxf(v[s - 1], v[s]);
      v[s - 1] = lo;
      v[s] = hi;
    }
  }
}

// 128x128 Gram tile: XOR-swizzled global_load_lds staging + MFMA K-loop.
__device__ __forceinline__ void gram_tile(
    const unsigned short* __restrict__ xb, int rowBase, int colBase,
    char* smem, f32x4 (&acc)[4][4]) {
  unsigned short* As = (unsigned short*)smem;
  unsigned short* Bs = (unsigned short*)(smem + 16384);
  const int t = threadIdx.x;
  const int lane = t & 63;
  const int w = t >> 6;
  const int wm = w >> 1, wn = w & 1;
  const int quad = lane >> 4, m16 = lane & 15;

  const f32x4 zero = {0.0f, 0.0f, 0.0f, 0.0f};
#pragma unroll
  for (int i = 0; i < 4; ++i)
#pragma unroll
    for (int j = 0; j < 4; ++j) acc[i][j] = zero;

  for (int kt = 0; kt < D_DIM / BK; ++kt) {
    const int k0 = kt * BK;
    __syncthreads();
#pragma unroll
    for (int q = 0; q < 4; ++q) {
      const int e = q * 2048 + t * 8;          // bf16 element index in [128][64] tile
      const int r = e >> 6;
      const int seg = (e >> 3) & 7;
      const int srcOff = r * D_DIM + ((seg ^ (r & 7)) * 8);
      gl_lds16(xb + (size_t)rowBase * D_DIM + k0 + srcOff, (char*)As + (size_t)e * 2);
      gl_lds16(xb + (size_t)colBase * D_DIM + k0 + srcOff, (char*)Bs + (size_t)e * 2);
    }
    __syncthreads();
#pragma unroll
    for (int kk = 0; kk < 2; ++kk) {
      short8 a[4], b[4];
#pragma unroll
      for (int i = 0; i < 4; ++i) {
        const int R = wm * 64 + i * 16 + m16;
        const int s = (kk * 4 + quad) ^ (R & 7);
        a[i] = *(const short8*)(As + R * 64 + s * 8);
      }
#pragma unroll
      for (int j = 0; j < 4; ++j) {
        const int R = wn * 64 + j * 16 + m16;
        const int s = (kk * 4 + quad) ^ (R & 7);
        b[j] = *(const short8*)(Bs + R * 64 + s * 8);
      }
#pragma unroll
      for (int i = 0; i < 4; ++i)
#pragma unroll
        for (int j = 0; j < 4; ++j)
          acc[i][j] = __builtin_amdgcn_mfma_f32_16x16x32_bf16(a[i], b[j], acc[i][j], 0, 0, 0);
    }
  }
}

// kernel 1: cast fp32 -> bf16, row sum-of-squares, init cnt/acc
__global__ __launch_bounds__(256) void cast_sq_kernel(
    const float* __restrict__ x, unsigned short* __restrict__ xb,
    float* __restrict__ sq, unsigned int* __restrict__ cnt,
    float* __restrict__ accw) {
  const int t = threadIdx.x;
  const int w = t >> 6, lane = t & 63;
  const int row = blockIdx.x * 4 + w;
  if (blockIdx.x == 0 && t == 0) { accw[0] = 0.0f; ((int*)accw)[1] = 0; }
  const f32x4* xr = (const f32x4*)(x + (size_t)row * D_DIM);
  ushort4v* xbr = (ushort4v*)(xb + (size_t)row * D_DIM);
  float s = 0.0f;
#pragma unroll
  for (int c = 0; c < 3; ++c) {
    const int idx = c * 64 + lane;
    f32x4 v = xr[idx];
    ushort4v u;
#pragma unroll
    for (int e = 0; e < 4; ++e) {
      __hip_bfloat16 h = __float2bfloat16(v[e]);
      unsigned short us;
      __builtin_memcpy(&us, &h, 2);
      u[e] = us;
      float vb = __bfloat162float(h);
      s += vb * vb;
    }
    xbr[idx] = u;
  }
#pragma unroll
  for (int off = 32; off > 0; off >>= 1) s += __shfl_down(s, off, 64);
  if (lane == 0) { sq[row] = s; cnt[row] = 0u; }
}

// kernel 2: symmetric pair kernel. One 128x128 Gram tile per block serves
// row-queries of tile a (keys = rows of b) AND row-queries of tile b
// (keys = rows of a). Survivors (s <= S_GATE) scatter to per-row global
// lists; no LDS epilogue stage at all.
__global__ __launch_bounds__(256) void knn_pair_kernel(
    const unsigned short* __restrict__ xb, const float* __restrict__ sq,
    unsigned int* __restrict__ cnt, float* __restrict__ cand) {
  __shared__ __align__(16) char smem[32768];

  const int t = threadIdx.x;
  const int lane = t & 63;
  const int w = t >> 6;
  const int wm = w >> 1, wn = w & 1;
  const int quad = lane >> 4, m16 = lane & 15;

  // linear pair index -> (a, b), a <= b
  int a = 0, b;
  {
    int rem = blockIdx.x, span = NTILE;
    while (rem >= span) { rem -= span; ++a; --span; }
    b = a + rem;
  }
  const int rowBase = a * BM, colBase = b * BN;
  const bool diag = (a == b);

  f32x4 acc[4][4];
  gram_tile(xb, rowBase, colBase, smem, acc);

  float csq[4];
#pragma unroll
  for (int j = 0; j < 4; ++j)
    csq[j] = sq[colBase + wn * 64 + j * 16 + m16];
  float rsqk[16];
#pragma unroll
  for (int i = 0; i < 4; ++i)
#pragma unroll
    for (int r = 0; r < 4; ++r)
      rsqk[i * 4 + r] = sq[rowBase + wm * 64 + i * 16 + quad * 4 + r];

  // row-side: queries = rows of a, keys = rows of b
#pragma unroll
  for (int i = 0; i < 4; ++i)
#pragma unroll
    for (int j = 0; j < 4; ++j)
#pragma unroll
      for (int r = 0; r < 4; ++r) {
        const float s = fmaf(-2.0f, acc[i][j][r], csq[j]);
        if (s <= S_GATE) {
          const int q = rowBase + wm * 64 + i * 16 + quad * 4 + r;
          const unsigned int slot = atomicAdd(&cnt[q], 1u);
          if (slot < SLOTS) cand[(size_t)q * SLOTS + slot] = s;
        }
      }
  // col-side: queries = rows of b, keys = rows of a (skip on diagonal)
  if (!diag) {
#pragma unroll
    for (int i = 0; i < 4; ++i)
#pragma unroll
      for (int j = 0; j < 4; ++j)
#pragma unroll
        for (int r = 0; r < 4; ++r) {
          const float s2 = fmaf(-2.0f, acc[i][j][r], rsqk[i * 4 + r]);
          if (s2 <= S_GATE) {
            const int q = colBase + wn * 64 + j * 16 + m16;
            const unsigned int slot = atomicAdd(&cnt[q], 1u);
            if (slot < SLOTS) cand[(size_t)q * SLOTS + slot] = s2;
          }
        }
  }
}

// kernel 3: per-row top-6 of the survivor list (8 threads/row) -> d -> log ->
// sum -> finalize. cnt<6 (gate too tight) or cnt>SLOTS (overflow) -> exact
// full-row recompute (correct for ANY input; never runs for this one).
__global__ __launch_bounds__(256) void knn_merge_kernel(
    const float* __restrict__ cand, const unsigned int* __restrict__ cnt,
    const float* __restrict__ sq, const unsigned short* __restrict__ xb,
    float* __restrict__ accw, float* __restrict__ out) {
  __shared__ float sub6[32][8][6];
  __shared__ float termS[32];
  const int t = threadIdx.x;
  const int row_l = t >> 3, seg = t & 7;
  const int row = blockIdx.x * 32 + row_l;

  const unsigned int n_raw = cnt[row];
  float v[6];
#pragma unroll
  for (int s = 0; s < 6; ++s) v[s] = 1e30f;

  if (n_raw >= 6u && n_raw <= (unsigned int)SLOTS) {
    const float* cr = cand + (size_t)row * SLOTS;
    for (unsigned int i = seg; i < n_raw; i += 8) ins6(cr[i], v);
  } else {
    // exact fallback: full row scan (includes self at c==row)
    const unsigned short* xr = xb + (size_t)row * D_DIM;
    for (int c = seg; c < B_DIM; c += 8) {
      const unsigned short* xc = xb + (size_t)c * D_DIM;
      float dot = 0.0f;
      for (int k = 0; k < D_DIM; ++k) dot = fmaf(bf2f(xr[k]), bf2f(xc[k]), dot);
      ins6(fmaf(-2.0f, dot, sq[c]), v);
    }
  }
#pragma unroll
  for (int s = 0; s < 6; ++s) sub6[row_l][seg][s] = v[s];
  __syncthreads();

  if (seg == 0) {
    float m[6];
#pragma unroll
    for (int s = 0; s < 6; ++s) m[s] = 1e30f;
#pragma unroll
    for (int g = 0; g < 8; ++g)
#pragma unroll
      for (int s = 0; s < 6; ++s) ins6(sub6[row_l][g][s], m);
    // m ascending in s-space; self (s ~ -rsq) is the minimum -> drop m[0]
    const float rsq = sq[row];
    const float mean =
        (sqrtf(fmaxf(m[1] + rsq, 0.0f)) + sqrtf(fmaxf(m[2] + rsq, 0.0f)) +
         sqrtf(fmaxf(m[3] + rsq, 0.0f)) + sqrtf(fmaxf(m[4] + rsq, 0.0f)) +
         sqrtf(fmaxf(m[5] + rsq, 0.0f))) * 0.2f;
    termS[row_l] = logf(mean + 1e-8f);
  }
  __syncthreads();

  if (t == 0) {
    float bs = 0.0f;
#pragma unroll
    for (int i = 0; i < 32; ++i) bs += termS[i];
    atomicAdd(accw, bs);
    __threadfence();
    const int old = atomicAdd((int*)accw + 1, 1);
    if (old == (int)gridDim.x - 1) {
      __threadfence();
      const float tot = atomicAdd(accw, 0.0f);
      out[0] = -tot * (1.0f / 8192.0f);
    }
  }
}

extern "C" void kernel_launch(void* const* d_in, const int* in_sizes, int n_in,
                              void* d_out, int out_size, void* d_ws, size_t ws_size,
                              hipStream_t stream) {
  const float* x = (const float*)d_in[0];
  float* out = (float*)d_out;
  char* ws = (char*)d_ws;
  unsigned short* xb = (unsigned short*)(ws + WS_XB);
  float* sq = (float*)(ws + WS_SQ);
  unsigned int* cnt = (unsigned int*)(ws + WS_CNT);
  float* cand = (float*)(ws + WS_CAND);
  float* accw = (float*)(ws + WS_ACC);

  cast_sq_kernel<<<B_DIM / 4, 256, 0, stream>>>(x, xb, sq, cnt, accw);
  knn_pair_kernel<<<NPAIR, 256, 0, stream>>>(xb, sq, cnt, cand);
  knn_merge_kernel<<<B_DIM / 32, 256, 0, stream>>>(cand, cnt, sq, xb, accw, out);
}